// Round 1
// baseline (676.583 us; speedup 1.0000x reference)
//
#include <hip/hip_runtime.h>
#include <math.h>

// ---------------------------------------------------------------------------
// GCNSim: 2-layer GCN (CSR-gather form) + pairwise concat + 2x top-1 MoE
// ---------------------------------------------------------------------------

__global__ void init_kernel(int* __restrict__ degi, int* __restrict__ fillctr, int n) {
    int i = blockIdx.x * blockDim.x + threadIdx.x;
    if (i < n) { degi[i] = 1; fillctr[i] = 0; }  // deg starts at 1: self-loop
}

__global__ void deg_kernel(const int* __restrict__ ei, int* __restrict__ degi, int nE) {
    int e = blockIdx.x * blockDim.x + threadIdx.x;
    if (e < nE) atomicAdd(&degi[ei[nE + e]], 1);  // dst half of edge_index
}

__global__ void dis_kernel(const int* __restrict__ degi, float* __restrict__ dis, int n) {
    int i = blockIdx.x * blockDim.x + threadIdx.x;
    if (i < n) dis[i] = rsqrtf((float)degi[i]);   // deg >= 1 so no clamp needed
}

// ---- 3-kernel exclusive scan of (deg-1) => CSR row offsets (real edges only)
__global__ void scan1_kernel(const int* __restrict__ degi, int* __restrict__ blocksum, int n) {
    int tid = threadIdx.x;
    int i = blockIdx.x * 1024 + tid;
    int v = (i < n) ? (degi[i] - 1) : 0;
    int lane = tid & 63, wid = tid >> 6;
    for (int d = 32; d > 0; d >>= 1) v += __shfl_down(v, d, 64);
    __shared__ int ws[16];
    if (lane == 0) ws[wid] = v;
    __syncthreads();
    if (tid == 0) {
        int s = 0;
        #pragma unroll
        for (int w = 0; w < 16; ++w) s += ws[w];
        blocksum[blockIdx.x] = s;
    }
}

__global__ void scan2_kernel(const int* __restrict__ blocksum, int* __restrict__ blockoff,
                             int* __restrict__ offsets, int nb, int n) {
    if (threadIdx.x == 0 && blockIdx.x == 0) {
        int acc = 0;
        for (int b = 0; b < nb; ++b) { blockoff[b] = acc; acc += blocksum[b]; }
        offsets[n] = acc;
    }
}

__global__ void scan3_kernel(const int* __restrict__ degi, const int* __restrict__ blockoff,
                             int* __restrict__ offsets, int n) {
    int tid = threadIdx.x;
    int i = blockIdx.x * 1024 + tid;
    int v = (i < n) ? (degi[i] - 1) : 0;
    int lane = tid & 63, wid = tid >> 6;
    int s = v;
    for (int d = 1; d < 64; d <<= 1) { int t = __shfl_up(s, (unsigned)d, 64); if (lane >= d) s += t; }
    __shared__ int ws[16];
    if (lane == 63) ws[wid] = s;
    __syncthreads();
    if (wid == 0) {
        int w = (lane < 16) ? ws[lane] : 0;
        for (int d = 1; d < 16; d <<= 1) { int t = __shfl_up(w, (unsigned)d, 64); if (lane >= d) w += t; }
        if (lane < 16) ws[lane] = w;
    }
    __syncthreads();
    int woff = (wid > 0) ? ws[wid - 1] : 0;
    if (i < n) offsets[i] = blockoff[blockIdx.x] + woff + (s - v);
}

__global__ void fill_kernel(const int* __restrict__ ei, const int* __restrict__ offsets,
                            int* __restrict__ fillctr, int* __restrict__ csr, int nE) {
    int e = blockIdx.x * blockDim.x + threadIdx.x;
    if (e < nE) {
        int d = ei[nE + e];
        int pos = offsets[d] + atomicAdd(&fillctr[d], 1);
        csr[pos] = ei[e];  // src
    }
}

// ---- hw1 = x @ w1  [N,256]x[256,32] -> [N,32]
__global__ __launch_bounds__(256) void hw1_kernel(const float* __restrict__ x,
                                                  const float* __restrict__ w1,
                                                  float* __restrict__ hw1, int n) {
    __shared__ float w1s[256 * 32];   // 32 KB
    __shared__ float xs[8 * 256];     // 8 KB
    int tid = threadIdx.x;
    for (int t = tid * 4; t < 8192; t += 1024)
        *(float4*)&w1s[t] = *(const float4*)&w1[t];
    int row0 = blockIdx.x * 8;
    for (int t = tid * 4; t < 2048; t += 1024) {
        int r = t >> 8, c = t & 255;
        int row = row0 + r;
        if (row < n) *(float4*)&xs[t] = *(const float4*)&x[(size_t)row * 256 + c];
    }
    __syncthreads();
    int r = tid >> 5, k = tid & 31;
    int row = row0 + r;
    if (row >= n) return;
    float acc = 0.f;
    #pragma unroll 4
    for (int c = 0; c < 256; c += 4) {
        float4 xv = *(float4*)&xs[r * 256 + c];
        acc += xv.x * w1s[(c    ) * 32 + k];
        acc += xv.y * w1s[(c + 1) * 32 + k];
        acc += xv.z * w1s[(c + 2) * 32 + k];
        acc += xv.w * w1s[(c + 3) * 32 + k];
    }
    hw1[(size_t)row * 32 + k] = acc;
}

// ---- layer-1 gather + ReLU + fused (h1 @ w2) -> hw2 [N,16]
__global__ __launch_bounds__(256) void gather1_kernel(const float* __restrict__ hw1,
                                                      const float* __restrict__ dis,
                                                      const int* __restrict__ offsets,
                                                      const int* __restrict__ csr,
                                                      const float* __restrict__ b1,
                                                      const float* __restrict__ w2,
                                                      float* __restrict__ hw2, int n) {
    __shared__ float h1s[8][33];
    __shared__ float w2s[32 * 16];
    int tid = threadIdx.x;
    for (int t = tid; t < 512; t += 256) w2s[t] = w2[t];
    int node0 = blockIdx.x * 8;
    int r = tid >> 5, k = tid & 31;
    int node = node0 + r;
    float h1v = 0.f;
    if (node < n) {
        int off = offsets[node], end = offsets[node + 1];
        float dn = dis[node];
        float accE = hw1[node * 32 + k] * dn;  // self-loop term (dis[node] applied twice)
        for (int e = off; e < end; ++e) {
            int s = csr[e];
            accE += hw1[s * 32 + k] * dis[s];
        }
        h1v = fmaxf(dn * accE + b1[k], 0.f);
    }
    h1s[r][k] = h1v;
    __syncthreads();
    if (tid < 128) {
        int rr = tid >> 4, kk = tid & 15;
        int nd = node0 + rr;
        if (nd < n) {
            float acc = 0.f;
            #pragma unroll
            for (int c = 0; c < 32; ++c) acc += h1s[rr][c] * w2s[c * 16 + kk];
            hw2[nd * 16 + kk] = acc;
        }
    }
}

// ---- layer-2 gather (no activation) -> h2 [N,16]
__global__ __launch_bounds__(256) void gather2_kernel(const float* __restrict__ hw2,
                                                      const float* __restrict__ dis,
                                                      const int* __restrict__ offsets,
                                                      const int* __restrict__ csr,
                                                      const float* __restrict__ b2,
                                                      float* __restrict__ h2, int n) {
    int tid = threadIdx.x;
    int node = blockIdx.x * 16 + (tid >> 4);
    int k = tid & 15;
    if (node >= n) return;
    int off = offsets[node], end = offsets[node + 1];
    float dn = dis[node];
    float accE = hw2[node * 16 + k] * dn;
    for (int e = off; e < end; ++e) {
        int s = csr[e];
        accE += hw2[s * 16 + k] * dis[s];
    }
    h2[node * 16 + k] = dn * accE + b2[k];
}

// ---- pairwise concat + MoE1 + MoE2 + log_softmax
__global__ __launch_bounds__(256) void pair_moe_kernel(const float* __restrict__ h2,
                                                       const int* __restrict__ nodes,
                                                       const float* __restrict__ gate1_w,
                                                       const float* __restrict__ e1_w,
                                                       const float* __restrict__ e1_b,
                                                       const float* __restrict__ gate2_w,
                                                       const float* __restrict__ e2_w,
                                                       const float* __restrict__ e2_b,
                                                       float* __restrict__ out1,
                                                       float* __restrict__ out2, int M) {
    __shared__ float hjs[50 * 16];
    __shared__ float g1s[32 * 4];
    __shared__ float e1ws[4 * 32 * 16];
    __shared__ float e1bs[4 * 16];
    __shared__ float g2s[16 * 4];
    __shared__ float e2ws[4 * 16 * 2];
    __shared__ float e2bs[4 * 2];
    int tid = threadIdx.x;
    for (int t = tid; t < 800; t += 256) { int j = t >> 4, c = t & 15; hjs[t] = h2[nodes[j] * 16 + c]; }
    for (int t = tid; t < 128; t += 256) g1s[t] = gate1_w[t];
    for (int t = tid; t < 2048; t += 256) e1ws[t] = e1_w[t];
    for (int t = tid; t < 64; t += 256) e1bs[t] = e1_b[t];
    for (int t = tid; t < 64; t += 256) g2s[t] = gate2_w[t];
    for (int t = tid; t < 128; t += 256) e2ws[t] = e2_w[t];
    if (tid < 8) e2bs[tid] = e2_b[tid];
    __syncthreads();

    int m = blockIdx.x * 256 + tid;
    if (m >= M) return;
    int i = m / 50, j = m - i * 50;

    float xs[32];
    int ni = nodes[i];
    float4 a0 = *(const float4*)&h2[ni * 16];
    float4 a1 = *(const float4*)&h2[ni * 16 + 4];
    float4 a2 = *(const float4*)&h2[ni * 16 + 8];
    float4 a3 = *(const float4*)&h2[ni * 16 + 12];
    xs[0]=a0.x; xs[1]=a0.y; xs[2]=a0.z; xs[3]=a0.w;
    xs[4]=a1.x; xs[5]=a1.y; xs[6]=a1.z; xs[7]=a1.w;
    xs[8]=a2.x; xs[9]=a2.y; xs[10]=a2.z; xs[11]=a2.w;
    xs[12]=a3.x; xs[13]=a3.y; xs[14]=a3.z; xs[15]=a3.w;
    #pragma unroll
    for (int c = 0; c < 16; ++c) xs[16 + c] = hjs[j * 16 + c];

    // write x_sim (output #2)
    #pragma unroll
    for (int c = 0; c < 32; c += 4)
        *(float4*)&out2[(size_t)m * 32 + c] = make_float4(xs[c], xs[c+1], xs[c+2], xs[c+3]);

    // MoE layer 1 (top-1)
    float g[4] = {0.f, 0.f, 0.f, 0.f};
    #pragma unroll
    for (int c = 0; c < 32; ++c) {
        float xv = xs[c];
        #pragma unroll
        for (int e = 0; e < 4; ++e) g[e] += xv * g1s[c * 4 + e];
    }
    int idx = 0; float best = g[0];
    #pragma unroll
    for (int e = 1; e < 4; ++e) if (g[e] > best) { best = g[e]; idx = e; }
    float z[16];
    #pragma unroll
    for (int o = 0; o < 16; ++o) {
        float a = e1bs[idx * 16 + o];
        #pragma unroll
        for (int c = 0; c < 32; ++c) a += xs[c] * e1ws[(idx * 32 + c) * 16 + o];
        z[o] = fmaxf(a, 0.f);
    }

    // MoE layer 2 (top-1)
    float g2[4] = {0.f, 0.f, 0.f, 0.f};
    #pragma unroll
    for (int c = 0; c < 16; ++c) {
        float zv = z[c];
        #pragma unroll
        for (int e = 0; e < 4; ++e) g2[e] += zv * g2s[c * 4 + e];
    }
    int idx2 = 0; float best2 = g2[0];
    #pragma unroll
    for (int e = 1; e < 4; ++e) if (g2[e] > best2) { best2 = g2[e]; idx2 = e; }
    float z2[2];
    #pragma unroll
    for (int o = 0; o < 2; ++o) {
        float a = e2bs[idx2 * 2 + o];
        #pragma unroll
        for (int c = 0; c < 16; ++c) a += z[c] * e2ws[(idx2 * 16 + c) * 2 + o];
        z2[o] = a;
    }

    // log_softmax over 2 classes
    float mx = fmaxf(z2[0], z2[1]);
    float l = logf(expf(z2[0] - mx) + expf(z2[1] - mx));
    out1[(size_t)m * 2 + 0] = z2[0] - mx - l;
    out1[(size_t)m * 2 + 1] = z2[1] - mx - l;
}

extern "C" void kernel_launch(void* const* d_in, const int* in_sizes, int n_in,
                              void* d_out, int out_size, void* d_ws, size_t ws_size,
                              hipStream_t stream) {
    const float* x       = (const float*)d_in[0];
    const float* w1      = (const float*)d_in[1];
    const float* b1      = (const float*)d_in[2];
    const float* w2      = (const float*)d_in[3];
    const float* b2      = (const float*)d_in[4];
    const float* gate1_w = (const float*)d_in[5];
    const float* e1_w    = (const float*)d_in[6];
    const float* e1_b    = (const float*)d_in[7];
    const float* gate2_w = (const float*)d_in[8];
    const float* e2_w    = (const float*)d_in[9];
    const float* e2_b    = (const float*)d_in[10];
    const int*   ei      = (const int*)d_in[11];
    const int*   nodes   = (const int*)d_in[12];

    const int n    = in_sizes[0] / 256;      // 100000
    const int nE   = in_sizes[11] / 2;       // 3200000
    const int nsel = in_sizes[12];           // 4096
    const int M    = nsel * 50;              // 204800

    // workspace layout (256B-aligned chunks)
    size_t off = 0;
    auto alloc = [&](size_t bytes) -> void* {
        void* p = (char*)d_ws + off;
        off += (bytes + 255) & ~(size_t)255;
        return p;
    };
    float* dis     = (float*)alloc((size_t)n * 4);
    int*   degi    = (int*)alloc((size_t)n * 4);
    int*   offsets = (int*)alloc((size_t)(n + 1) * 4);
    int*   fillctr = (int*)alloc((size_t)n * 4);
    int*   blocksum= (int*)alloc(256 * 4);
    int*   blockoff= (int*)alloc(256 * 4);
    int*   csr     = (int*)alloc((size_t)nE * 4);
    float* hw1     = (float*)alloc((size_t)n * 32 * 4);
    float* hw2     = (float*)alloc((size_t)n * 16 * 4);
    float* h2      = (float*)alloc((size_t)n * 16 * 4);
    if (off > ws_size) return;  // workspace too small: fail loudly (validation will catch)

    float* out1 = (float*)d_out;              // [M,2] log_softmax
    float* out2 = out1 + (size_t)M * 2;       // [M,32] x_sim

    const int nb = (n + 1023) / 1024;         // scan blocks (98)

    init_kernel<<<(n + 255) / 256, 256, 0, stream>>>(degi, fillctr, n);
    deg_kernel<<<(nE + 255) / 256, 256, 0, stream>>>(ei, degi, nE);
    dis_kernel<<<(n + 255) / 256, 256, 0, stream>>>(degi, dis, n);
    scan1_kernel<<<nb, 1024, 0, stream>>>(degi, blocksum, n);
    scan2_kernel<<<1, 64, 0, stream>>>(blocksum, blockoff, offsets, nb, n);
    scan3_kernel<<<nb, 1024, 0, stream>>>(degi, blockoff, offsets, n);
    fill_kernel<<<(nE + 255) / 256, 256, 0, stream>>>(ei, offsets, fillctr, csr, nE);
    hw1_kernel<<<(n + 7) / 8, 256, 0, stream>>>(x, w1, hw1, n);
    gather1_kernel<<<(n + 7) / 8, 256, 0, stream>>>(hw1, dis, offsets, csr, b1, w2, hw2, n);
    gather2_kernel<<<(n + 15) / 16, 256, 0, stream>>>(hw2, dis, offsets, csr, b2, h2, n);
    pair_moe_kernel<<<(M + 255) / 256, 256, 0, stream>>>(h2, nodes, gate1_w, e1_w, e1_b,
                                                         gate2_w, e2_w, e2_b, out1, out2, M);
}